// Round 14
// baseline (823.653 us; speedup 1.0000x reference)
//
#include <hip/hip_runtime.h>
#include <hip/hip_bf16.h>

// Problem: B=8192 rows, D=4096. 3 layers of relu(l2norm(h) @ W^T + b).
// ROUND 14: faithful m201 8-phase port on R6's verified memory layout.
// 256x256 tile, BK=64, 8 waves, 128 KiB LDS dbuf, 16x16x32 MFMA.
// Per K-tile: 4 phases, each {ds-reads | stage | BAR | lgkm0 | setprio |
// 16-MFMA C-quadrant | setprio | BAR}; vmcnt(6) ONCE per tile (phase 4) --
// 3 half-tiles stay in flight across barriers (T3+T4). Quadrants:
// ph1 (a03,b01) reads a03+b01(12); ph2 (a47,b01) reads a47(8);
// ph3 (a47,b23) reads b23(4); ph4 (a03,b23) reads none.
// Stage slots (issue order = ledger order): ph1: (t+1).B.h1;
// ph3: (t+2).A.h0,(t+2).A.h1; ph4: (t+2).B.h0.
//
// FIFO ledger (2 loads/half/thread; induction): entering tile t, in-flight
// = (t+1).{Ah0,Ah1,Bh0} (6). ph1 +2 -> 8; ph3 +4 -> 12; ph4 +2 -> 14;
// VMW(6) retires 8 = all of tile t+1; leaves 6 = (t+2)x3. Prologue:
// t0 x4 halves, VMW(4) [Ah0,Ah1 land]; t1 x{Ah0,Ah1,Bh0}, VMW(6)
// [t0 complete]; BAR. Tail t>=NT-2: VMW(0), stages skipped. Loop VMEM
// stream is PURE global_load_lds in program order (bias moved to epilogue
// -- R7 lesson: counted waits must not depend on cross-class issue order).
// WAR (stage after a barrier following victims' readers' lgkm0):
//  (t+2).A @ph3-top: A(t) last read a47 @ph2-top gated ph2-lgkm0 < ph2-BAR2 ✓
//  (t+2).B.h0 @ph4-top: B(t) last read b23 @ph3-top gated ph3-lgkm0 < BAR2 ✓
//  (t+1).B.h1 @ph1-top: victim B(t-1).h1 gated ph3(t-1)-lgkm0, many BARs ✓
// RAW: tile t+1 reads at ph1-top(t+1) follow VMW(6)@ph4(t) (retired t+1)
//  + two barriers (publish) ✓.

#define NROWS 8192
#define DIM   4096

typedef __bf16 bf16x8 __attribute__((ext_vector_type(8)));
typedef float  f32x4  __attribute__((ext_vector_type(4)));

__device__ static inline short f2bf(float f) {
  __hip_bfloat16 h = __float2bfloat16(f);
  return __builtin_bit_cast(short, h);
}

#define BARRIER() do { asm volatile("" ::: "memory"); \
                       __builtin_amdgcn_s_barrier();  \
                       asm volatile("" ::: "memory"); } while (0)
#define GATE()   do { asm volatile("s_waitcnt lgkmcnt(0)" ::: "memory"); \
                      __builtin_amdgcn_sched_barrier(0); } while (0)
#define VMW(N)   do { asm volatile("s_waitcnt vmcnt(" #N ")" ::: "memory"); \
                      __builtin_amdgcn_sched_barrier(0); } while (0)

__global__ __launch_bounds__(512, 2)
void gemm256_bias_relu(const short* __restrict__ A,
                       const short* __restrict__ Bw,
                       const float* __restrict__ bias,
                       float* __restrict__ C,
                       int M, int N, int K)
{
  __shared__ short lds[4][16384];   // [buf*2+op][256 rows * 64 bf16] = 128 KiB

  // XCD-aware swizzle (bijective: grid % 8 == 0 here)
  int bid = blockIdx.x;
  const int nwg = gridDim.x;
  if ((nwg & 7) == 0) { const int cpx = nwg >> 3; bid = (bid & 7) * cpx + (bid >> 3); }
  const int nbn  = N >> 8;
  const int brow = (bid / nbn) << 8;
  const int bcol = (bid % nbn) << 8;

  const int lane = threadIdx.x & 63;
  const int wid  = __builtin_amdgcn_readfirstlane(threadIdx.x >> 6);  // uniform
  const int wr   = wid >> 2;           // 0..1 : 128-row output band
  const int wc   = wid & 3;            // 0..3 : 64-col output band

  f32x4 acc[8][4] = {};

  const size_t rowK = (size_t)K * 2;   // bytes per global row
  char* const  ldsB = (char*)&lds[0][0];

  // ---- staging addressing (coalesced, source pre-swizzled) ----
  const int r8  = lane >> 3;
  const int kcs = (lane & 7) ^ r8;
  const char* AgL = (const char*)A  + (size_t)(brow + r8) * rowK + (size_t)kcs * 16;
  const char* BgL = (const char*)Bw + (size_t)(bcol + r8) * rowK + (size_t)kcs * 16;
  int rbo[4], rbb[4];                  // wave-uniform (wid-derived) -> SGPR
#pragma unroll
  for (int i = 0; i < 4; ++i) {
    const int rb = wid * 8 + i * 64;
    rbo[i] = rb * (int)rowK;
    rbb[i] = rb * 128;
  }

  // stage one 128-row half: 2 x global_load_lds(16B) per thread
  auto stage_half = [&](int parity, int op, int h, int tile) {
    const char* gp = (op ? BgL : AgL) + ((size_t)tile << 7);
    char* lb = ldsB + (parity * 2 + op) * 32768;
#pragma unroll
    for (int s = 0; s < 2; ++s) {
      const int idx = h * 2 + s;
      __builtin_amdgcn_global_load_lds(
          (const __attribute__((address_space(1))) void*)(gp + rbo[idx]),
          (__attribute__((address_space(3))) void*)(lb + rbb[idx]), 16, 0, 0);
    }
  };

  // ---- fragment read addressing (swizzled: phys kc = kc ^ (row&7)) ----
  const int l15  = lane & 15;
  const int xlo  = ((lane >> 4) ^ (lane & 3)) * 16;
  const int b2   = (lane >> 2) & 1;
  const int k64[2] = { b2 << 6, (1 - b2) << 6 };
  const int abase = (wr * 128 + l15) * 128 + xlo;
  const int bbase = (wc * 64  + l15) * 128 + xlo;

  const int NT = K >> 6;

  bf16x8 a03[4][2], a47[4][2], bF[4][2];   // 96 VGPR, same budget as R6

#define LOAD_A4(DST, PTR, I0)                                                \
  _Pragma("unroll")                                                          \
  for (int ii = 0; ii < 4; ++ii)                                             \
    _Pragma("unroll")                                                        \
    for (int ks = 0; ks < 2; ++ks)                                           \
      DST[ii][ks] = *reinterpret_cast<const bf16x8*>(                        \
          (PTR) + abase + ((I0) + ii) * 2048 + k64[ks]);

#define LOAD_B2(PTR, J0)                                                     \
  _Pragma("unroll")                                                          \
  for (int jj = 0; jj < 2; ++jj)                                             \
    _Pragma("unroll")                                                        \
    for (int ks = 0; ks < 2; ++ks)                                           \
      bF[(J0) + jj][ks] = *reinterpret_cast<const bf16x8*>(                  \
          (PTR) + bbase + ((J0) + jj) * 2048 + k64[ks]);

// one C-quadrant: 16 MFMA (ks outer -> same-acc revisit distance 8)
#define MFMAQ(I0, J0, AF)                                                    \
  _Pragma("unroll")                                                          \
  for (int ks = 0; ks < 2; ++ks)                                             \
    _Pragma("unroll")                                                        \
    for (int ii = 0; ii < 4; ++ii)                                           \
      _Pragma("unroll")                                                      \
      for (int jj = 0; jj < 2; ++jj)                                         \
        acc[(I0) + ii][(J0) + jj] = __builtin_amdgcn_mfma_f32_16x16x32_bf16( \
            AF[ii][ks], bF[(J0) + jj][ks], acc[(I0) + ii][(J0) + jj], 0, 0, 0);

  // ---- prologue (two-step counted, pure gload_lds stream) ----
  stage_half(0, 0, 0, 0); stage_half(0, 0, 1, 0);    // t0.Ah0, t0.Ah1
  stage_half(0, 1, 0, 0); stage_half(0, 1, 1, 0);    // t0.Bh0, t0.Bh1
  if (NT > 1) { VMW(4); }                            // t0.A lands
  if (NT > 1) { stage_half(1, 0, 0, 1); stage_half(1, 0, 1, 1);
                stage_half(1, 1, 0, 1); }            // t1.Ah0,Ah1,Bh0
  if (NT > 1) { VMW(6); } else { VMW(0); }           // t0 complete
  BARRIER();

  for (int t = 0; t < NT; ++t) {
    const int cur = t & 1, nxt = cur ^ 1;
    const char* At = ldsB + (cur * 2 + 0) * 32768;
    const char* Bt = ldsB + (cur * 2 + 1) * 32768;

    // ---- phase 1: reads a03+b01 (12); stage (t+1).B.h1 ----
    LOAD_A4(a03, At, 0)
    LOAD_B2(Bt, 0)
    if (t + 1 < NT) stage_half(nxt, 1, 1, t + 1);
    BARRIER();
    GATE();
    __builtin_amdgcn_s_setprio(1);
    MFMAQ(0, 0, a03)
    __builtin_amdgcn_s_setprio(0);
    BARRIER();

    // ---- phase 2: reads a47 (8) ----
    LOAD_A4(a47, At, 4)
    BARRIER();
    GATE();
    __builtin_amdgcn_s_setprio(1);
    MFMAQ(4, 0, a47)
    __builtin_amdgcn_s_setprio(0);
    BARRIER();

    // ---- phase 3: reads b23 (4); stage (t+2).A.h0 + A.h1 ----
    LOAD_B2(Bt, 2)
    if (t + 2 < NT) { stage_half(cur, 0, 0, t + 2); stage_half(cur, 0, 1, t + 2); }
    BARRIER();
    GATE();
    __builtin_amdgcn_s_setprio(1);
    MFMAQ(4, 2, a47)
    __builtin_amdgcn_s_setprio(0);
    BARRIER();

    // ---- phase 4: stage (t+2).B.h0; counted vmcnt (once per tile) ----
    if (t + 2 < NT) stage_half(cur, 1, 0, t + 2);
    if (t >= NT - 2) { VMW(0); } else { VMW(6); }
    BARRIER();
    __builtin_amdgcn_s_setprio(1);
    MFMAQ(0, 2, a03)
    __builtin_amdgcn_s_setprio(0);
    BARRIER();
  }
#undef MFMAQ
#undef LOAD_A4
#undef LOAD_B2

  // epilogue (bias loaded HERE so the loop's VMEM stream is pure gload_lds)
  float bv[4];
#pragma unroll
  for (int j = 0; j < 4; ++j)
    bv[j] = bias[bcol + wc * 64 + j * 16 + (lane & 15)];
  // C/D layout: col = lane&15, row = (lane>>4)*4 + reg
#pragma unroll
  for (int i = 0; i < 8; ++i) {
    const int rbase = brow + wr * 128 + i * 16 + ((lane >> 4) << 2);
#pragma unroll
    for (int j = 0; j < 4; ++j) {
      const int col = bcol + wc * 64 + j * 16 + (lane & 15);
#pragma unroll
      for (int r = 0; r < 4; ++r) {
        const float v = acc[i][j][r] + bv[j];
        C[(size_t)(rbase + r) * N + col] = v > 0.f ? v : 0.f;
      }
    }
  }
}

// ---------------------------------------------------------------------------
// Row L2-normalize (fp32 in) -> bf16 out. One block (256 thr) per row of 4096.
// ---------------------------------------------------------------------------
__global__ __launch_bounds__(256)
void rownorm_bf16(const float* __restrict__ in, short* __restrict__ out)
{
  const int row = blockIdx.x;
  const int t0  = threadIdx.x;
  const float4* inr = (const float4*)(in + (size_t)row * DIM);

  float4 v[4];
  float ss = 0.f;
#pragma unroll
  for (int t = 0; t < 4; ++t) {
    v[t] = inr[t0 + t * 256];
    ss += v[t].x * v[t].x + v[t].y * v[t].y + v[t].z * v[t].z + v[t].w * v[t].w;
  }
#pragma unroll
  for (int off = 32; off > 0; off >>= 1)
    ss += __shfl_down(ss, off, 64);

  __shared__ float wss[4];
  if ((t0 & 63) == 0) wss[t0 >> 6] = ss;
  __syncthreads();
  const float tot   = wss[0] + wss[1] + wss[2] + wss[3];
  const float scale = 1.f / fmaxf(sqrtf(tot), 1e-12f);  // F.normalize eps

  short4* outr = (short4*)(out + (size_t)row * DIM);
#pragma unroll
  for (int t = 0; t < 4; ++t) {
    short4 o;
    o.x = f2bf(v[t].x * scale);
    o.y = f2bf(v[t].y * scale);
    o.z = f2bf(v[t].z * scale);
    o.w = f2bf(v[t].w * scale);
    outr[t0 + t * 256] = o;
  }
}

// ---------------------------------------------------------------------------
// fp32 -> bf16 bulk cast (for W), vectorized, grid-stride.
// ---------------------------------------------------------------------------
__global__ __launch_bounds__(256)
void cast_bf16(const float* __restrict__ in, short* __restrict__ out, int n4)
{
  int i = blockIdx.x * 256 + threadIdx.x;
  const int stride = gridDim.x * 256;
  for (; i < n4; i += stride) {
    const float4 v = ((const float4*)in)[i];
    short4 o;
    o.x = f2bf(v.x);
    o.y = f2bf(v.y);
    o.z = f2bf(v.z);
    o.w = f2bf(v.w);
    ((short4*)out)[i] = o;
  }
}

extern "C" void kernel_launch(void* const* d_in, const int* in_sizes, int n_in,
                              void* d_out, int out_size, void* d_ws, size_t ws_size,
                              hipStream_t stream) {
  const float* x = (const float*)d_in[0];
  const float* W[3]    = { (const float*)d_in[1], (const float*)d_in[3], (const float*)d_in[5] };
  const float* bias[3] = { (const float*)d_in[2], (const float*)d_in[4], (const float*)d_in[6] };
  float* out = (float*)d_out;

  // workspace layout: hn bf16 [8192][4096] (64 MiB) | Wb bf16 [4096][4096] (32 MiB)
  short* hn = (short*)d_ws;
  short* Wb = (short*)((char*)d_ws + (size_t)NROWS * DIM * 2);

  const size_t layer_elems = (size_t)NROWS * DIM;
  const float* hin = x;

  for (int L = 0; L < 3; ++L) {
    cast_bf16<<<2048, 256, 0, stream>>>(W[L], Wb, DIM * DIM / 4);
    rownorm_bf16<<<NROWS, 256, 0, stream>>>(hin, hn);
    gemm256_bias_relu<<<(NROWS / 256) * (DIM / 256), 512, 0, stream>>>(
        hn, Wb, bias[L], out + (size_t)L * layer_elems, NROWS, DIM, DIM);
    hin = out + (size_t)L * layer_elems;
  }
}